// Round 7
// baseline (647.488 us; speedup 1.0000x reference)
//
#include <hip/hip_runtime.h>

typedef __bf16 bf16;
typedef __bf16 bf16x8 __attribute__((ext_vector_type(8)));
typedef float floatx4 __attribute__((ext_vector_type(4)));

__device__ __forceinline__ floatx4 mfma16(bf16x8 a, bf16x8 b, floatx4 c) {
    return __builtin_amdgcn_mfma_f32_16x16x32_bf16(a, b, c, 0, 0, 0);
}

__device__ __forceinline__ void load16_lds(const void* g, void* l) {
    __builtin_amdgcn_global_load_lds(
        (const __attribute__((address_space(1))) void*)g,
        (__attribute__((address_space(3))) void*)(unsigned int)(unsigned long long)l,
        16, 0, 0);
}

#define PIPE_BARRIER do { asm volatile("" ::: "memory"); \
    __builtin_amdgcn_s_barrier(); asm volatile("" ::: "memory"); } while (0)

// ---------------------------------------------------------------------------
// Dtype detector: fp32 buffers viewed as bf16 show wild exponents -> flag=1.
// ---------------------------------------------------------------------------
__global__ __launch_bounds__(256) void detect_dtype(const bf16* __restrict__ p,
                                                    int* __restrict__ flag) {
    __shared__ int bad;
    if (threadIdx.x == 0) bad = 0;
    __syncthreads();
    int lbad = 0;
    for (int i = threadIdx.x; i < 4096; i += 256) {
        const float v = (float)p[i];
        if (!isfinite(v) || fabsf(v) > 1e10f) lbad = 1;
    }
    if (lbad) atomicOr(&bad, 1);
    __syncthreads();
    if (threadIdx.x == 0) *flag = bad;
}

// ---------------------------------------------------------------------------
// Small vectors -> bf16 arena. bpr@0 bep@1024 fb1@2048(4096) fb2@6144
// l1g@7168 l1b@8192 l2g@9216 l2b@10240 l3g@11264 l3b@12288. 13312 total.
// ---------------------------------------------------------------------------
__global__ __launch_bounds__(256) void convert_vecs(
    const void* bpr, const void* bep, const void* fb1, const void* fb2,
    const void* g1, const void* b1, const void* g2, const void* b2,
    const void* g3, const void* b3, bf16* __restrict__ out,
    const int* __restrict__ flagp) {
    const int fl = *flagp;
    const int idx = blockIdx.x * 256 + threadIdx.x;
    const void* src;
    int off;
    if (idx < 1024)      { src = bpr; off = idx; }
    else if (idx < 2048) { src = bep; off = idx - 1024; }
    else if (idx < 6144) { src = fb1; off = idx - 2048; }
    else if (idx < 7168) { src = fb2; off = idx - 6144; }
    else {
        const void* t[6] = {g1, b1, g2, b2, g3, b3};
        src = t[(idx - 7168) >> 10];
        off = idx & 1023;
    }
    out[idx] = fl ? (bf16)((const float*)src)[off] : ((const bf16*)src)[off];
}

// ---------------------------------------------------------------------------
// LayerNorm, fp32 input (for resf).
// ---------------------------------------------------------------------------
__global__ __launch_bounds__(256) void ln_f32(const float* __restrict__ X,
                                              const bf16* __restrict__ G,
                                              const bf16* __restrict__ Bv,
                                              bf16* __restrict__ Y) {
    const int row = blockIdx.x;
    const int tid = threadIdx.x;
    const float* x = X + (size_t)row * 1024 + tid * 4;
    float v[4];
#pragma unroll
    for (int i = 0; i < 4; i++) v[i] = x[i];
    float s = v[0] + v[1] + v[2] + v[3];
    float q = v[0] * v[0] + v[1] * v[1] + v[2] * v[2] + v[3] * v[3];
#pragma unroll
    for (int off = 32; off >= 1; off >>= 1) {
        s += __shfl_xor(s, off);
        q += __shfl_xor(q, off);
    }
    __shared__ float ss[4], qq[4];
    const int wave = tid >> 6, lane = tid & 63;
    if (lane == 0) { ss[wave] = s; qq[wave] = q; }
    __syncthreads();
    s = ss[0] + ss[1] + ss[2] + ss[3];
    q = qq[0] + qq[1] + qq[2] + qq[3];
    const float mu = s * (1.0f / 1024.0f);
    const float var = q * (1.0f / 1024.0f) - mu * mu;
    const float rs = rsqrtf(var + 1e-5f);
    bf16* y = Y + (size_t)row * 1024 + tid * 4;
    const bf16* g = G + tid * 4;
    const bf16* b = Bv + tid * 4;
#pragma unroll
    for (int i = 0; i < 4; i++)
        y[i] = (bf16)((v[i] - mu) * rs * (float)g[i] + (float)b[i]);
}

// ---------------------------------------------------------------------------
// LayerNorm, raw input with device-side dtype dispatch (fp32/bf16 per flag).
// ---------------------------------------------------------------------------
__global__ __launch_bounds__(256) void ln_dyn(const void* __restrict__ X,
                                              const bf16* __restrict__ G,
                                              const bf16* __restrict__ Bv,
                                              bf16* __restrict__ Y,
                                              const int* __restrict__ flagp) {
    const int fl = *flagp;
    const int row = blockIdx.x;
    const int tid = threadIdx.x;
    float v[4];
    if (fl) {
        const float* x = (const float*)X + (size_t)row * 1024 + tid * 4;
#pragma unroll
        for (int i = 0; i < 4; i++) v[i] = x[i];
    } else {
        const bf16* x = (const bf16*)X + (size_t)row * 1024 + tid * 4;
#pragma unroll
        for (int i = 0; i < 4; i++) v[i] = (float)x[i];
    }
    float s = v[0] + v[1] + v[2] + v[3];
    float q = v[0] * v[0] + v[1] * v[1] + v[2] * v[2] + v[3] * v[3];
#pragma unroll
    for (int off = 32; off >= 1; off >>= 1) {
        s += __shfl_xor(s, off);
        q += __shfl_xor(q, off);
    }
    __shared__ float ss[4], qq[4];
    const int wave = tid >> 6, lane = tid & 63;
    if (lane == 0) { ss[wave] = s; qq[wave] = q; }
    __syncthreads();
    s = ss[0] + ss[1] + ss[2] + ss[3];
    q = qq[0] + qq[1] + qq[2] + qq[3];
    const float mu = s * (1.0f / 1024.0f);
    const float var = q * (1.0f / 1024.0f) - mu * mu;
    const float rs = rsqrtf(var + 1e-5f);
    bf16* y = Y + (size_t)row * 1024 + tid * 4;
    const bf16* g = G + tid * 4;
    const bf16* b = Bv + tid * 4;
#pragma unroll
    for (int i = 0; i < 4; i++)
        y[i] = (bf16)((v[i] - mu) * rs * (float)g[i] + (float)b[i]);
}

// ---------------------------------------------------------------------------
// One-shot transpose+convert of ALL 7 weights into the W_T arena.
// ---------------------------------------------------------------------------
__global__ __launch_bounds__(256) void transpose_all(
    const void* w0, const void* w1, const void* w2, const void* w3,
    const void* w4, const void* w5, const void* w6,
    bf16* __restrict__ out_base, const int* __restrict__ flagp) {
    const int fl = *flagp;
    const int cum[8] = {0, 3072, 4096, 6144, 7168, 8192, 12288, 16384};
    const int ntv[7] = {96, 32, 64, 32, 32, 128, 32};
    const int ldi[7] = {3072, 1024, 2048, 1024, 1024, 4096, 1024};
    const int ldo[7] = {1024, 1024, 1024, 1024, 1024, 1024, 4096};
    const size_t ooff[7] = {0, 3145728, 4194304, 6291456, 7340032, 8388608, 12582912};
    const void* ws[7] = {w0, w1, w2, w3, w4, w5, w6};

    const int g = blockIdx.x;
    int w = 0;
#pragma unroll
    for (int i = 1; i < 7; i++) if (g >= cum[i]) w = i;
    const int t = g - cum[w];
    const int xt = t % ntv[w], yt = t / ntv[w];
    const int n0 = xt * 32, k0 = yt * 32;
    const void* in = ws[w];
    bf16* out = out_base + ooff[w];
    const int ldin = ldi[w], ldout = ldo[w];

    __shared__ bf16 tile[32][33];
    const int x = threadIdx.x, y = threadIdx.y;
#pragma unroll
    for (int i = 0; i < 4; i++) {
        const size_t idx = (size_t)(k0 + y + 8 * i) * ldin + n0 + x;
        tile[y + 8 * i][x] = fl ? (bf16)((const float*)in)[idx]
                                : ((const bf16*)in)[idx];
    }
    __syncthreads();
#pragma unroll
    for (int i = 0; i < 4; i++)
        out[(size_t)(n0 + y + 8 * i) * ldout + k0 + x] = tile[x][y + 8 * i];
}

// ---------------------------------------------------------------------------
// GEMM: C[M,N] = A @ Bt^T. Tile 128 x TN (TN = 128 or 64), BK=32, depth-2
// double-buffered pipeline with counted vmcnt (round-4 schedule).
//
// Round-7 change: BK 64 -> 32, halving LDS to 32 KiB (TN=128) / 24 KiB
// (TN=64) -> 5-6 blocks/CU instead of 2. Rationale (re-derived roofline):
// FFN1 MFMA floor = 29 us/CU-share, LDS-port = 24 us, measured 112 us at
// 20% occupancy (2 waves/SIMD) -> ~70% of cycles are correlated stalls
// (post-barrier ds_read latency, barrier skew) that TLP can fill. BK=32
// restores round-0's residency (28% occ) while keeping the counted-vmcnt
// never-drain pipeline (round-3's +23%). Tile order reverted to round-4
// (round-6 M-chunking RAISED fetch 57.6->77 MB and regressed).
//
// Swizzle re-derived for 64 B rows: staged chunk c ^= (row>>1)&3 on BOTH
// the global source (linear gload_lds dest) and the ds_read slot. Bank
// audit (b128): even rows occupy banks 0-15, odd 16-31; per chunk-group
// 8 lanes x 4 words over 16 banks = 8 words/bank = balanced (conflict-free
// in the b128 sense), same invariant as the verified BK=64 scheme.
// Loads/tile L = 2 + TN/64 -> in-loop s_waitcnt vmcnt(L) waits only for
// tile t+1 (issued a full iteration earlier); never drains to 0 mid-loop.
// Epilogue: +bias, relu, +resd (raw dtype), +resf, out f32/bf16/dual.
// ---------------------------------------------------------------------------
template <int TN>
__global__ __launch_bounds__(256) void gemm_bt(
    const bf16* __restrict__ A, int lda,
    const bf16* __restrict__ Bt, int ldb,
    const bf16* __restrict__ bias,
    const void* resd,
    const float* resf,
    bf16* outb, float* outf, void* dual,
    const int* __restrict__ flagp,
    int M, int N, int K, int relu) {
    constexpr int NJ = TN / 32;          // MFMA col-tiles per wave: 4 or 2
    constexpr int NBI = TN / 64;         // B stage insts per tile: 2 or 1
    __shared__ bf16 As[2][128 * 32];
    __shared__ bf16 Bs[2][TN * 32];
    const int fl = *flagp;
    const int tid = threadIdx.x;
    const int wave = tid >> 6, lane = tid & 63;
    const int quad = lane >> 4, l16 = lane & 15;
    const int g = blockIdx.x;
    const int yb = g % 56, xb = g / 56;
    const int m0 = yb * 128, n0 = xb * TN;
    const int wm = (wave >> 1) * 64, wn = (wave & 1) * (TN / 2);

    // Staging: thread covers 16B chunk (tid&3) of row (tid>>2) [+64 for the
    // 2nd inst]; global source chunk pre-swizzled: c ^= (row>>1)&3 (same
    // value at row and row+64); LDS dest linear (gload_lds base + lane*16).
    const int srow = tid >> 2;
    const int sc = (tid & 3) ^ ((srow >> 1) & 3);
    const bf16* gA = A + (size_t)(m0 + srow) * lda + sc * 8;
    const bf16* gB = Bt + (size_t)(n0 + srow) * ldb + sc * 8;

    const int NT = K >> 5;

#define STAGE_TILE(T) do { \
    const int _b = (T) & 1; \
    const int _k = (T) << 5; \
    load16_lds(gA + _k, &As[_b][tid * 8]); \
    load16_lds(gA + _k + (size_t)64 * lda, &As[_b][tid * 8 + 2048]); \
    load16_lds(gB + _k, &Bs[_b][tid * 8]); \
    if (NBI == 2) \
        load16_lds(gB + _k + (size_t)64 * ldb, &Bs[_b][tid * 8 + 2048]); \
} while (0)

    floatx4 acc[4][NJ] = {};

    // Prologue: stage tiles 0,1; wait tile 0 (leave tile 1 in flight).
    STAGE_TILE(0);
    STAGE_TILE(1);
    if constexpr (TN == 128) asm volatile("s_waitcnt vmcnt(4)" ::: "memory");
    else                     asm volatile("s_waitcnt vmcnt(3)" ::: "memory");
    PIPE_BARRIER;

    for (int t = 0; t < NT; ++t) {
        const int cur = t & 1;
        bf16x8 af[4], bfr[NJ];
#pragma unroll
        for (int i = 0; i < 4; i++) {
            const int r = wm + i * 16 + l16;
            const int slot = quad ^ ((r >> 1) & 3);
            af[i] = *(const bf16x8*)(&As[cur][r * 32 + slot * 8]);
        }
#pragma unroll
        for (int j = 0; j < NJ; j++) {
            const int r = wn + j * 16 + l16;
            const int slot = quad ^ ((r >> 1) & 3);
            bfr[j] = *(const bf16x8*)(&Bs[cur][r * 32 + slot * 8]);
        }
#pragma unroll
        for (int i = 0; i < 4; i++)
#pragma unroll
            for (int j = 0; j < NJ; j++)
                acc[i][j] = mfma16(af[i], bfr[j], acc[i][j]);
        PIPE_BARRIER;   // all waves past MFMAs => reads of buf[cur] done
        if (t + 2 < NT) {
            STAGE_TILE(t + 2);
            if constexpr (TN == 128) asm volatile("s_waitcnt vmcnt(4)" ::: "memory");
            else                     asm volatile("s_waitcnt vmcnt(3)" ::: "memory");
        } else {
            asm volatile("s_waitcnt vmcnt(0)" ::: "memory");
        }
        PIPE_BARRIER;   // buf[cur^1] (tile t+1) fully staged for all waves
    }
#undef STAGE_TILE

#pragma unroll
    for (int i = 0; i < 4; i++) {
        const int mbase = m0 + wm + i * 16 + quad * 4;
#pragma unroll
        for (int j = 0; j < NJ; j++) {
            const int n = n0 + wn + j * 16 + l16;
            const float bv = bias ? (float)bias[n] : 0.0f;
#pragma unroll
            for (int r = 0; r < 4; r++) {
                const size_t idx = (size_t)(mbase + r) * N + n;
                float v = acc[i][j][r] + bv;
                if (relu && v < 0.0f) v = 0.0f;
                if (resd) v += fl ? ((const float*)resd)[idx]
                                  : (float)((const bf16*)resd)[idx];
                if (resf) v += resf[idx];
                if (dual) {
                    if (fl) ((float*)dual)[idx] = v;
                    else ((bf16*)dual)[idx] = (bf16)v;
                } else if (outf) {
                    outf[idx] = v;
                } else {
                    outb[idx] = (bf16)v;
                }
            }
        }
    }
}

// ---------------------------------------------------------------------------
// Attention: one block per (bh, 32-query tile). 4 waves. T=448, HD=64, H=16.
// ---------------------------------------------------------------------------
__global__ __launch_bounds__(256) void attn_kernel(
    const bf16* __restrict__ Q, int qstride,
    const bf16* __restrict__ Kp, int kstride,
    const bf16* __restrict__ Vp, int vstride,
    bf16* __restrict__ O, int causal) {
    const int T_ = 448, HD = 64, OC = 1024;
    const float scale = 0.03125f;  // C^-0.5 (full-embed scaling per reference)
    const int bh = blockIdx.y, b = bh >> 4, h = bh & 15;
    const int q0 = blockIdx.x * 32;
    const int tid = threadIdx.x, wave = tid >> 6, lane = tid & 63;
    const int quad = lane >> 4, l16 = lane & 15;

    __shared__ bf16 Pb[32][464];
    __shared__ bf16 VT[64][40];
    __shared__ float redp[32][4];
    __shared__ float Mbuf[32], Lbuf[32];

    const bf16* qb = Q + (size_t)(b * T_ + q0) * qstride + h * HD;
    const bf16* kb = Kp + (size_t)(b * T_) * kstride + h * HD;
    const bf16* vb = Vp + (size_t)(b * T_) * vstride + h * HD;

    bf16x8 qf[2][2];
#pragma unroll
    for (int qi = 0; qi < 2; qi++)
#pragma unroll
        for (int kh = 0; kh < 2; kh++)
            qf[qi][kh] = *(const bf16x8*)(qb + (size_t)(qi * 16 + l16) * qstride + kh * 32 + quad * 8);

    float S[2][7][4];
#pragma unroll
    for (int kt = 0; kt < 7; kt++) {
        const int s = wave * 112 + kt * 16 + l16;
        const bf16* kr = kb + (size_t)s * kstride + quad * 8;
        bf16x8 kf0 = *(const bf16x8*)kr;
        bf16x8 kf1 = *(const bf16x8*)(kr + 32);
#pragma unroll
        for (int qi = 0; qi < 2; qi++) {
            floatx4 c = {};
            c = mfma16(qf[qi][0], kf0, c);
            c = mfma16(qf[qi][1], kf1, c);
#pragma unroll
            for (int r = 0; r < 4; r++) {
                float v = c[r] * scale;
                if (causal) {
                    const int t = q0 + qi * 16 + quad * 4 + r;
                    if (s > t) v = -30000.0f;
                }
                S[qi][kt][r] = v;
            }
        }
    }

    float mx[2][4];
#pragma unroll
    for (int qi = 0; qi < 2; qi++)
#pragma unroll
        for (int r = 0; r < 4; r++) {
            float m = S[qi][0][r];
#pragma unroll
            for (int kt = 1; kt < 7; kt++) m = fmaxf(m, S[qi][kt][r]);
#pragma unroll
            for (int off = 1; off < 16; off <<= 1) m = fmaxf(m, __shfl_xor(m, off));
            mx[qi][r] = m;
        }
    if (l16 == 0) {
#pragma unroll
        for (int qi = 0; qi < 2; qi++)
#pragma unroll
            for (int r = 0; r < 4; r++) redp[qi * 16 + quad * 4 + r][wave] = mx[qi][r];
    }
    __syncthreads();
    if (tid < 32)
        Mbuf[tid] = fmaxf(fmaxf(redp[tid][0], redp[tid][1]),
                          fmaxf(redp[tid][2], redp[tid][3]));
    __syncthreads();

#pragma unroll
    for (int qi = 0; qi < 2; qi++)
#pragma unroll
        for (int r = 0; r < 4; r++) {
            const float Mv = Mbuf[qi * 16 + quad * 4 + r];
            float acc = 0.0f;
#pragma unroll
            for (int kt = 0; kt < 7; kt++) {
                const float p = __expf(fminf(S[qi][kt][r] - Mv, 0.0f));
                acc += p;
                Pb[qi * 16 + quad * 4 + r][wave * 112 + kt * 16 + l16] = (bf16)p;
            }
#pragma unroll
            for (int off = 1; off < 16; off <<= 1) acc += __shfl_xor(acc, off);
            if (l16 == 0) redp[qi * 16 + quad * 4 + r][wave] = acc;
        }
    __syncthreads();
    if (tid < 32)
        Lbuf[tid] = redp[tid][0] + redp[tid][1] + redp[tid][2] + redp[tid][3];

    floatx4 oacc[2] = {};
    const int qi3 = wave & 1, djb = (wave >> 1) * 2;
    for (int kt = 0; kt < 14; kt++) {
        const int s0 = kt * 32;
        const bf16* vsrc = vb + (size_t)(s0 + (tid & 31)) * vstride + (tid >> 5) * 8;
        bf16x8 vv = *(const bf16x8*)vsrc;
        __syncthreads();
#pragma unroll
        for (int e = 0; e < 8; e++) VT[(tid >> 5) * 8 + e][tid & 31] = vv[e];
        __syncthreads();
        bf16x8 pa = *(const bf16x8*)(&Pb[qi3 * 16 + l16][s0 + quad * 8]);
#pragma unroll
        for (int u = 0; u < 2; u++) {
            bf16x8 bv = *(const bf16x8*)(&VT[(djb + u) * 16 + l16][quad * 8]);
            oacc[u] = mfma16(pa, bv, oacc[u]);
        }
    }

#pragma unroll
    for (int u = 0; u < 2; u++) {
        const int d = (djb + u) * 16 + l16;
#pragma unroll
        for (int r = 0; r < 4; r++) {
            const int t = q0 + qi3 * 16 + quad * 4 + r;
            const float L = Lbuf[qi3 * 16 + quad * 4 + r];
            O[(size_t)(b * T_ + t) * OC + h * HD + d] = (bf16)(oacc[u][r] / L);
        }
    }
}

// ---------------------------------------------------------------------------
// Arena (~130.1 MB): W_T [0,32) | resf [32,60) | Cb/Hb [60,102/116) |
// Db [102,116) | x3b [116,130) | vecs+flag @130.
// ---------------------------------------------------------------------------
extern "C" void kernel_launch(void* const* d_in, const int* in_sizes, int n_in,
                              void* d_out, int out_size, void* d_ws, size_t ws_size,
                              hipStream_t stream) {
    const void* tgt_r  = d_in[0];
    const void* src_r  = d_in[1];
    const void* wqkv_r = d_in[2];
    const void* wpr_r  = d_in[3];
    const void* bpr_r  = d_in[4];
    const void* wkv_r  = d_in[5];
    const void* wq_r   = d_in[6];
    const void* wep_r  = d_in[7];
    const void* bep_r  = d_in[8];
    const void* fw1_r  = d_in[9];
    const void* fb1_r  = d_in[10];
    const void* fw2_r  = d_in[11];
    const void* fb2_r  = d_in[12];
    const void* l1g_r  = d_in[13];
    const void* l1b_r  = d_in[14];
    const void* l2g_r  = d_in[15];
    const void* l2b_r  = d_in[16];
    const void* l3g_r  = d_in[17];
    const void* l3b_r  = d_in[18];

    const size_t MB = 1u << 20;
    char* base = (char*)d_ws;
    bf16*  WT   = (bf16*)(base + 0 * MB);
    float* resf = (float*)(base + 32 * MB);
    bf16*  Cb   = (bf16*)(base + 60 * MB);
    bf16*  Hb   = Cb;
    bf16*  Db   = (bf16*)(base + 102 * MB);
    bf16*  x3b  = (bf16*)(base + 116 * MB);
    bf16*  vecs = (bf16*)(base + 130 * MB);
    int*   flag = (int*)(base + 130 * MB + 65536);
    bf16*  kvb  = Cb + (size_t)7168 * 1024;

    bf16* T_qkv = WT + 0;
    bf16* T_pr  = WT + 3145728;
    bf16* T_kv  = WT + 4194304;
    bf16* T_q   = WT + 6291456;
    bf16* T_ep  = WT + 7340032;
    bf16* T_f1  = WT + 8388608;
    bf16* T_f2  = WT + 12582912;

    bf16* v_bpr = vecs + 0;
    bf16* v_bep = vecs + 1024;
    bf16* v_fb1 = vecs + 2048;
    bf16* v_fb2 = vecs + 6144;
    bf16 *v_l1g = vecs + 7168,  *v_l1b = vecs + 8192;
    bf16 *v_l2g = vecs + 9216,  *v_l2b = vecs + 10240;
    bf16 *v_l3g = vecs + 11264, *v_l3b = vecs + 12288;

    const int M = 7168;
    dim3 blk(256);
    dim3 tb(32, 8);

    // 0. dtype detection, vec conversion, all weight transposes
    detect_dtype<<<1, blk, 0, stream>>>((const bf16*)tgt_r, flag);
    convert_vecs<<<52, blk, 0, stream>>>(bpr_r, bep_r, fb1_r, fb2_r, l1g_r, l1b_r,
                                         l2g_r, l2b_r, l3g_r, l3b_r, vecs, flag);
    transpose_all<<<16384, tb, 0, stream>>>(wqkv_r, wpr_r, wkv_r, wq_r, wep_r,
                                            fw1_r, fw2_r, WT, flag);

    // 1. x1 = LN1(tgt)
    ln_dyn<<<M, blk, 0, stream>>>(tgt_r, v_l1g, v_l1b, Db, flag);
    // 2. qkv = x1 @ wqkv  (N=3072, 1344 blocks)
    gemm_bt<128><<<24 * 56, blk, 0, stream>>>(
        Db, 1024, T_qkv, 1024, nullptr, nullptr, nullptr, Cb, nullptr, nullptr,
        flag, M, 3072, 1024, 0);
    // 3. self-attn (causal)
    attn_kernel<<<dim3(14, 256), blk, 0, stream>>>(Cb, 3072, Cb + 1024, 3072, Cb + 2048, 3072, Db, 1);
    // 4. resf = attn1 @ wproj + bpr + tgt  (N=1024 -> TN=64, 896 blocks)
    gemm_bt<64><<<16 * 56, blk, 0, stream>>>(
        Db, 1024, T_pr, 1024, v_bpr, tgt_r, nullptr, nullptr, resf, nullptr,
        flag, M, 1024, 1024, 0);
    // 5. xq = LN2(resf)
    ln_f32<<<M, blk, 0, stream>>>(resf, v_l2g, v_l2b, Db);
    // 6. xs = LN2(src)
    ln_dyn<<<M, blk, 0, stream>>>(src_r, v_l2g, v_l2b, Cb, flag);
    // 7. kv = xs @ wkv  (N=2048, 896 blocks)
    gemm_bt<128><<<16 * 56, blk, 0, stream>>>(
        Cb, 1024, T_kv, 1024, nullptr, nullptr, nullptr, kvb, nullptr, nullptr,
        flag, M, 2048, 1024, 0);
    // 8. q2 = xq @ wq  (TN=64, 896 blocks)
    gemm_bt<64><<<16 * 56, blk, 0, stream>>>(
        Db, 1024, T_q, 1024, nullptr, nullptr, nullptr, Cb, nullptr, nullptr,
        flag, M, 1024, 1024, 0);
    // 9. cross-attn
    attn_kernel<<<dim3(14, 256), blk, 0, stream>>>(Cb, 1024, kvb, 2048, kvb + 1024, 2048, Db, 0);
    // 10. resf += attn2 @ wedproj + bep  (TN=64, 896 blocks, in-place)
    gemm_bt<64><<<16 * 56, blk, 0, stream>>>(
        Db, 1024, T_ep, 1024, v_bep, nullptr, resf, nullptr, resf, nullptr,
        flag, M, 1024, 1024, 0);
    // 11. x3 = LN3(tgt)
    ln_dyn<<<M, blk, 0, stream>>>(tgt_r, v_l3g, v_l3b, x3b, flag);
    // 12. h = relu(x3 @ fw1 + fb1)  (N=4096, 1792 blocks)
    gemm_bt<128><<<32 * 56, blk, 0, stream>>>(
        x3b, 1024, T_f1, 1024, v_fb1, nullptr, nullptr, Hb, nullptr, nullptr,
        flag, M, 4096, 1024, 1);
    // 13. out = h @ fw2 + fb2 + resf -> d_out  (K=4096, TN=64, 896 blocks)
    gemm_bt<64><<<16 * 56, blk, 0, stream>>>(
        Hb, 4096, T_f2, 4096, v_fb2, nullptr, resf, nullptr, nullptr, d_out,
        flag, M, 1024, 4096, 0);
}

// Round 8
// 577.725 us; speedup vs baseline: 1.1208x; 1.1208x over previous
//
#include <hip/hip_runtime.h>

typedef __bf16 bf16;
typedef __bf16 bf16x8 __attribute__((ext_vector_type(8)));
typedef float floatx4 __attribute__((ext_vector_type(4)));

__device__ __forceinline__ floatx4 mfma16(bf16x8 a, bf16x8 b, floatx4 c) {
    return __builtin_amdgcn_mfma_f32_16x16x32_bf16(a, b, c, 0, 0, 0);
}

__device__ __forceinline__ void load16_lds(const void* g, void* l) {
    __builtin_amdgcn_global_load_lds(
        (const __attribute__((address_space(1))) void*)g,
        (__attribute__((address_space(3))) void*)(unsigned int)(unsigned long long)l,
        16, 0, 0);
}

#define PIPE_BARRIER do { asm volatile("" ::: "memory"); \
    __builtin_amdgcn_s_barrier(); asm volatile("" ::: "memory"); } while (0)

// ---------------------------------------------------------------------------
// Dtype detector: fp32 buffers viewed as bf16 show wild exponents -> flag=1.
// ---------------------------------------------------------------------------
__global__ __launch_bounds__(256) void detect_dtype(const bf16* __restrict__ p,
                                                    int* __restrict__ flag) {
    __shared__ int bad;
    if (threadIdx.x == 0) bad = 0;
    __syncthreads();
    int lbad = 0;
    for (int i = threadIdx.x; i < 4096; i += 256) {
        const float v = (float)p[i];
        if (!isfinite(v) || fabsf(v) > 1e10f) lbad = 1;
    }
    if (lbad) atomicOr(&bad, 1);
    __syncthreads();
    if (threadIdx.x == 0) *flag = bad;
}

// ---------------------------------------------------------------------------
// Small vectors -> bf16 arena. bpr@0 bep@1024 fb1@2048(4096) fb2@6144
// l1g@7168 l1b@8192 l2g@9216 l2b@10240 l3g@11264 l3b@12288. 13312 total.
// ---------------------------------------------------------------------------
__global__ __launch_bounds__(256) void convert_vecs(
    const void* bpr, const void* bep, const void* fb1, const void* fb2,
    const void* g1, const void* b1, const void* g2, const void* b2,
    const void* g3, const void* b3, bf16* __restrict__ out,
    const int* __restrict__ flagp) {
    const int fl = *flagp;
    const int idx = blockIdx.x * 256 + threadIdx.x;
    const void* src;
    int off;
    if (idx < 1024)      { src = bpr; off = idx; }
    else if (idx < 2048) { src = bep; off = idx - 1024; }
    else if (idx < 6144) { src = fb1; off = idx - 2048; }
    else if (idx < 7168) { src = fb2; off = idx - 6144; }
    else {
        const void* t[6] = {g1, b1, g2, b2, g3, b3};
        src = t[(idx - 7168) >> 10];
        off = idx & 1023;
    }
    out[idx] = fl ? (bf16)((const float*)src)[off] : ((const bf16*)src)[off];
}

// ---------------------------------------------------------------------------
// Fused LN1+LN3: both normalize tgt; shared (x-mu)*rs core computed once,
// two gamma/beta applications, two outputs. Saves a full 29 MB tgt pass and
// a launch vs two ln_dyn calls. Arithmetic identical to ln_dyn per output.
// ---------------------------------------------------------------------------
__global__ __launch_bounds__(256) void ln_dual(
    const void* __restrict__ X,
    const bf16* __restrict__ G1, const bf16* __restrict__ B1,
    const bf16* __restrict__ G3, const bf16* __restrict__ B3,
    bf16* __restrict__ Y1, bf16* __restrict__ Y3,
    const int* __restrict__ flagp) {
    const int fl = *flagp;
    const int row = blockIdx.x;
    const int tid = threadIdx.x;
    float v[4];
    if (fl) {
        const float* x = (const float*)X + (size_t)row * 1024 + tid * 4;
#pragma unroll
        for (int i = 0; i < 4; i++) v[i] = x[i];
    } else {
        const bf16* x = (const bf16*)X + (size_t)row * 1024 + tid * 4;
#pragma unroll
        for (int i = 0; i < 4; i++) v[i] = (float)x[i];
    }
    float s = v[0] + v[1] + v[2] + v[3];
    float q = v[0] * v[0] + v[1] * v[1] + v[2] * v[2] + v[3] * v[3];
#pragma unroll
    for (int off = 32; off >= 1; off >>= 1) {
        s += __shfl_xor(s, off);
        q += __shfl_xor(q, off);
    }
    __shared__ float ss[4], qq[4];
    const int wave = tid >> 6, lane = tid & 63;
    if (lane == 0) { ss[wave] = s; qq[wave] = q; }
    __syncthreads();
    s = ss[0] + ss[1] + ss[2] + ss[3];
    q = qq[0] + qq[1] + qq[2] + qq[3];
    const float mu = s * (1.0f / 1024.0f);
    const float var = q * (1.0f / 1024.0f) - mu * mu;
    const float rs = rsqrtf(var + 1e-5f);
    bf16* y1 = Y1 + (size_t)row * 1024 + tid * 4;
    bf16* y3 = Y3 + (size_t)row * 1024 + tid * 4;
#pragma unroll
    for (int i = 0; i < 4; i++) {
        const float core = (v[i] - mu) * rs;
        y1[i] = (bf16)(core * (float)G1[tid * 4 + i] + (float)B1[tid * 4 + i]);
        y3[i] = (bf16)(core * (float)G3[tid * 4 + i] + (float)B3[tid * 4 + i]);
    }
}

// ---------------------------------------------------------------------------
// Fused LN2 pair: blocks [0,7168) LN resf (always fp32) -> Yf;
// blocks [7168,14336) LN src (raw dtype per flag) -> Yr. One launch.
// ---------------------------------------------------------------------------
__global__ __launch_bounds__(256) void ln2_pair(
    const float* __restrict__ Xf, const void* __restrict__ Xr,
    const bf16* __restrict__ G, const bf16* __restrict__ Bv,
    bf16* __restrict__ Yf, bf16* __restrict__ Yr,
    const int* __restrict__ flagp) {
    const int row = blockIdx.x;
    const int tid = threadIdx.x;
    float v[4];
    bf16* y;
    if (row < 7168) {
        const float* x = Xf + (size_t)row * 1024 + tid * 4;
#pragma unroll
        for (int i = 0; i < 4; i++) v[i] = x[i];
        y = Yf + (size_t)row * 1024 + tid * 4;
    } else {
        const int r2 = row - 7168;
        if (*flagp) {
            const float* x = (const float*)Xr + (size_t)r2 * 1024 + tid * 4;
#pragma unroll
            for (int i = 0; i < 4; i++) v[i] = x[i];
        } else {
            const bf16* x = (const bf16*)Xr + (size_t)r2 * 1024 + tid * 4;
#pragma unroll
            for (int i = 0; i < 4; i++) v[i] = (float)x[i];
        }
        y = Yr + (size_t)r2 * 1024 + tid * 4;
    }
    float s = v[0] + v[1] + v[2] + v[3];
    float q = v[0] * v[0] + v[1] * v[1] + v[2] * v[2] + v[3] * v[3];
#pragma unroll
    for (int off = 32; off >= 1; off >>= 1) {
        s += __shfl_xor(s, off);
        q += __shfl_xor(q, off);
    }
    __shared__ float ss[4], qq[4];
    const int wave = tid >> 6, lane = tid & 63;
    if (lane == 0) { ss[wave] = s; qq[wave] = q; }
    __syncthreads();
    s = ss[0] + ss[1] + ss[2] + ss[3];
    q = qq[0] + qq[1] + qq[2] + qq[3];
    const float mu = s * (1.0f / 1024.0f);
    const float var = q * (1.0f / 1024.0f) - mu * mu;
    const float rs = rsqrtf(var + 1e-5f);
#pragma unroll
    for (int i = 0; i < 4; i++)
        y[i] = (bf16)((v[i] - mu) * rs * (float)G[tid * 4 + i] +
                      (float)Bv[tid * 4 + i]);
}

// ---------------------------------------------------------------------------
// One-shot transpose+convert of ALL 7 weights into the W_T arena.
// ---------------------------------------------------------------------------
__global__ __launch_bounds__(256) void transpose_all(
    const void* w0, const void* w1, const void* w2, const void* w3,
    const void* w4, const void* w5, const void* w6,
    bf16* __restrict__ out_base, const int* __restrict__ flagp) {
    const int fl = *flagp;
    const int cum[8] = {0, 3072, 4096, 6144, 7168, 8192, 12288, 16384};
    const int ntv[7] = {96, 32, 64, 32, 32, 128, 32};
    const int ldi[7] = {3072, 1024, 2048, 1024, 1024, 4096, 1024};
    const int ldo[7] = {1024, 1024, 1024, 1024, 1024, 1024, 4096};
    const size_t ooff[7] = {0, 3145728, 4194304, 6291456, 7340032, 8388608, 12582912};
    const void* ws[7] = {w0, w1, w2, w3, w4, w5, w6};

    const int g = blockIdx.x;
    int w = 0;
#pragma unroll
    for (int i = 1; i < 7; i++) if (g >= cum[i]) w = i;
    const int t = g - cum[w];
    const int xt = t % ntv[w], yt = t / ntv[w];
    const int n0 = xt * 32, k0 = yt * 32;
    const void* in = ws[w];
    bf16* out = out_base + ooff[w];
    const int ldin = ldi[w], ldout = ldo[w];

    __shared__ bf16 tile[32][33];
    const int x = threadIdx.x, y = threadIdx.y;
#pragma unroll
    for (int i = 0; i < 4; i++) {
        const size_t idx = (size_t)(k0 + y + 8 * i) * ldin + n0 + x;
        tile[y + 8 * i][x] = fl ? (bf16)((const float*)in)[idx]
                                : ((const bf16*)in)[idx];
    }
    __syncthreads();
#pragma unroll
    for (int i = 0; i < 4; i++)
        out[(size_t)(n0 + y + 8 * i) * ldout + k0 + x] = tile[x][y + 8 * i];
}

// ---------------------------------------------------------------------------
// GEMM: C[M,N] = A @ Bt^T. Tile 128 x TN (TN = 128 or 64), BK=64, depth-2
// double-buffered pipeline with counted vmcnt — ROUND-4 SCHEDULE, the best
// measured (FFN1 112.8 us). K-loop variants falsified in 4 directions:
// drain-frequency (r2), scheduler pins (r1/r5), 256^2 8-phase geometry
// (r1/r5), BK=32 occupancy (r7: +11pt occ but MfmaUtil 22->19, -18%).
// Counted-vmcnt depth-2 was the one win (r3: +23%). DO NOT touch this loop.
// Per K-tile t:
//   ds_read frags from buf[t&1] + MFMA (compiler-scheduled, fine lgkmcnt)
//   -> barrier -> stage tile t+2 into buf[t&1] (async global_load_lds)
//   -> s_waitcnt vmcnt(LOADS) (waits only tile t+1, issued a full iter ago)
//   -> barrier.  Never drains vmcnt to 0 mid-loop.
// LDS XOR-swizzle (0-conflict, verified): global source chunk c ^= row&7,
// linear gload_lds dest, matching slot XOR on ds_read.
// Epilogue: +bias, relu, +resd (raw dtype), +resf, out f32/bf16/dual.
// ---------------------------------------------------------------------------
template <int TN>
__global__ __launch_bounds__(256) void gemm_bt(
    const bf16* __restrict__ A, int lda,
    const bf16* __restrict__ Bt, int ldb,
    const bf16* __restrict__ bias,
    const void* resd,
    const float* resf,
    bf16* outb, float* outf, void* dual,
    const int* __restrict__ flagp,
    int M, int N, int K, int relu) {
    constexpr int NJ = TN / 32;
    constexpr int NB = TN / 32;
    __shared__ bf16 As[2][128 * 64];
    __shared__ bf16 Bs[2][TN * 64];
    const int fl = *flagp;
    const int tid = threadIdx.x;
    const int wave = tid >> 6, lane = tid & 63;
    const int quad = lane >> 4, l16 = lane & 15;
    const int g = blockIdx.x;
    const int yb = g % 56, xb = g / 56;
    const int m0 = yb * 128, n0 = xb * TN;
    const int wm = (wave >> 1) * 64, wn = (wave & 1) * (TN / 2);

    const int srow = tid >> 3;
    const int sc = (tid & 7) ^ (srow & 7);
    const bf16* gA = A + (size_t)(m0 + srow) * lda + sc * 8;
    const bf16* gB = Bt + (size_t)(n0 + srow) * ldb + sc * 8;

    const int NT = K >> 6;

#define STAGE_TILE(T) do { \
    const int _b = (T) & 1; \
    const int _k = (T) << 6; \
    _Pragma("unroll") \
    for (int i = 0; i < 4; i++) \
        load16_lds(gA + _k + (size_t)(32 * i) * lda, \
                   &As[_b][tid * 8 + i * 2048]); \
    _Pragma("unroll") \
    for (int i = 0; i < NB; i++) \
        load16_lds(gB + _k + (size_t)(32 * i) * ldb, \
                   &Bs[_b][tid * 8 + i * 2048]); \
} while (0)

    floatx4 acc[4][NJ] = {};

    STAGE_TILE(0);
    STAGE_TILE(1);
    if constexpr (TN == 128) asm volatile("s_waitcnt vmcnt(8)" ::: "memory");
    else                     asm volatile("s_waitcnt vmcnt(6)" ::: "memory");
    PIPE_BARRIER;

    for (int t = 0; t < NT; ++t) {
        const int cur = t & 1;
        bf16x8 af[4][2], bfr[NJ][2];
#pragma unroll
        for (int i = 0; i < 4; i++)
#pragma unroll
            for (int h = 0; h < 2; h++) {
                const int r = wm + i * 16 + l16;
                const int slot = ((h << 2) + quad) ^ (r & 7);
                af[i][h] = *(const bf16x8*)(&As[cur][r * 64 + slot * 8]);
            }
#pragma unroll
        for (int j = 0; j < NJ; j++)
#pragma unroll
            for (int h = 0; h < 2; h++) {
                const int r = wn + j * 16 + l16;
                const int slot = ((h << 2) + quad) ^ (r & 7);
                bfr[j][h] = *(const bf16x8*)(&Bs[cur][r * 64 + slot * 8]);
            }
#pragma unroll
        for (int i = 0; i < 4; i++)
#pragma unroll
            for (int j = 0; j < NJ; j++) {
                acc[i][j] = mfma16(af[i][0], bfr[j][0], acc[i][j]);
                acc[i][j] = mfma16(af[i][1], bfr[j][1], acc[i][j]);
            }
        PIPE_BARRIER;   // all waves past MFMAs => reads of buf[cur] done
        if (t + 2 < NT) {
            STAGE_TILE(t + 2);
            if constexpr (TN == 128) asm volatile("s_waitcnt vmcnt(8)" ::: "memory");
            else                     asm volatile("s_waitcnt vmcnt(6)" ::: "memory");
        } else {
            asm volatile("s_waitcnt vmcnt(0)" ::: "memory");
        }
        PIPE_BARRIER;   // buf[cur^1] (tile t+1) fully staged for all waves
    }
#undef STAGE_TILE

#pragma unroll
    for (int i = 0; i < 4; i++) {
        const int mbase = m0 + wm + i * 16 + quad * 4;
#pragma unroll
        for (int j = 0; j < NJ; j++) {
            const int n = n0 + wn + j * 16 + l16;
            const float bv = bias ? (float)bias[n] : 0.0f;
#pragma unroll
            for (int r = 0; r < 4; r++) {
                const size_t idx = (size_t)(mbase + r) * N + n;
                float v = acc[i][j][r] + bv;
                if (relu && v < 0.0f) v = 0.0f;
                if (resd) v += fl ? ((const float*)resd)[idx]
                                  : (float)((const bf16*)resd)[idx];
                if (resf) v += resf[idx];
                if (dual) {
                    if (fl) ((float*)dual)[idx] = v;
                    else ((bf16*)dual)[idx] = (bf16)v;
                } else if (outf) {
                    outf[idx] = v;
                } else {
                    outb[idx] = (bf16)v;
                }
            }
        }
    }
}

// ---------------------------------------------------------------------------
// Attention: one block per (bh, 32-query tile). 4 waves. T=448, HD=64, H=16.
// Round-8: causal tile-skip. Masked columns carry P = exp(-30000-M) = 0.0
// exactly, so dropping them is bit-identical:
//  - QK: skip K-tiles where min s (= wave*112+kt*16) > q0+31; preset S.
//  - PV: loop kt < blockIdx.x+1 (tile all-masked iff kt*32 >= q0+32).
// Average work in causal QK/PV drops to ~54%.
// ---------------------------------------------------------------------------
__global__ __launch_bounds__(256) void attn_kernel(
    const bf16* __restrict__ Q, int qstride,
    const bf16* __restrict__ Kp, int kstride,
    const bf16* __restrict__ Vp, int vstride,
    bf16* __restrict__ O, int causal) {
    const int T_ = 448, HD = 64, OC = 1024;
    const float scale = 0.03125f;  // C^-0.5 (full-embed scaling per reference)
    const int bh = blockIdx.y, b = bh >> 4, h = bh & 15;
    const int q0 = blockIdx.x * 32;
    const int tid = threadIdx.x, wave = tid >> 6, lane = tid & 63;
    const int quad = lane >> 4, l16 = lane & 15;

    __shared__ bf16 Pb[32][464];
    __shared__ bf16 VT[64][40];
    __shared__ float redp[32][4];
    __shared__ float Mbuf[32], Lbuf[32];

    const bf16* qb = Q + (size_t)(b * T_ + q0) * qstride + h * HD;
    const bf16* kb = Kp + (size_t)(b * T_) * kstride + h * HD;
    const bf16* vb = Vp + (size_t)(b * T_) * vstride + h * HD;

    bf16x8 qf[2][2];
#pragma unroll
    for (int qi = 0; qi < 2; qi++)
#pragma unroll
        for (int kh = 0; kh < 2; kh++)
            qf[qi][kh] = *(const bf16x8*)(qb + (size_t)(qi * 16 + l16) * qstride + kh * 32 + quad * 8);

    float S[2][7][4];
    const int tmax = q0 + 31;
#pragma unroll
    for (int kt = 0; kt < 7; kt++) {
        const int s_tile = wave * 112 + kt * 16;
        if (causal && s_tile > tmax) {
#pragma unroll
            for (int qi = 0; qi < 2; qi++)
#pragma unroll
                for (int r = 0; r < 4; r++) S[qi][kt][r] = -30000.0f;
            continue;
        }
        const int s = s_tile + l16;
        const bf16* kr = kb + (size_t)s * kstride + quad * 8;
        bf16x8 kf0 = *(const bf16x8*)kr;
        bf16x8 kf1 = *(const bf16x8*)(kr + 32);
#pragma unroll
        for (int qi = 0; qi < 2; qi++) {
            floatx4 c = {};
            c = mfma16(qf[qi][0], kf0, c);
            c = mfma16(qf[qi][1], kf1, c);
#pragma unroll
            for (int r = 0; r < 4; r++) {
                float v = c[r] * scale;
                if (causal) {
                    const int t = q0 + qi * 16 + quad * 4 + r;
                    if (s > t) v = -30000.0f;
                }
                S[qi][kt][r] = v;
            }
        }
    }

    float mx[2][4];
#pragma unroll
    for (int qi = 0; qi < 2; qi++)
#pragma unroll
        for (int r = 0; r < 4; r++) {
            float m = S[qi][0][r];
#pragma unroll
            for (int kt = 1; kt < 7; kt++) m = fmaxf(m, S[qi][kt][r]);
#pragma unroll
            for (int off = 1; off < 16; off <<= 1) m = fmaxf(m, __shfl_xor(m, off));
            mx[qi][r] = m;
        }
    if (l16 == 0) {
#pragma unroll
        for (int qi = 0; qi < 2; qi++)
#pragma unroll
            for (int r = 0; r < 4; r++) redp[qi * 16 + quad * 4 + r][wave] = mx[qi][r];
    }
    __syncthreads();
    if (tid < 32)
        Mbuf[tid] = fmaxf(fmaxf(redp[tid][0], redp[tid][1]),
                          fmaxf(redp[tid][2], redp[tid][3]));
    __syncthreads();

#pragma unroll
    for (int qi = 0; qi < 2; qi++)
#pragma unroll
        for (int r = 0; r < 4; r++) {
            const float Mv = Mbuf[qi * 16 + quad * 4 + r];
            float acc = 0.0f;
#pragma unroll
            for (int kt = 0; kt < 7; kt++) {
                const float p = __expf(fminf(S[qi][kt][r] - Mv, 0.0f));
                acc += p;
                Pb[qi * 16 + quad * 4 + r][wave * 112 + kt * 16 + l16] = (bf16)p;
            }
#pragma unroll
            for (int off = 1; off < 16; off <<= 1) acc += __shfl_xor(acc, off);
            if (l16 == 0) redp[qi * 16 + quad * 4 + r][wave] = acc;
        }
    __syncthreads();
    if (tid < 32)
        Lbuf[tid] = redp[tid][0] + redp[tid][1] + redp[tid][2] + redp[tid][3];

    floatx4 oacc[2] = {};
    const int qi3 = wave & 1, djb = (wave >> 1) * 2;
    const int ktpv = causal ? (blockIdx.x + 1) : 14;
    for (int kt = 0; kt < ktpv; kt++) {
        const int s0 = kt * 32;
        const bf16* vsrc = vb + (size_t)(s0 + (tid & 31)) * vstride + (tid >> 5) * 8;
        bf16x8 vv = *(const bf16x8*)vsrc;
        __syncthreads();
#pragma unroll
        for (int e = 0; e < 8; e++) VT[(tid >> 5) * 8 + e][tid & 31] = vv[e];
        __syncthreads();
        bf16x8 pa = *(const bf16x8*)(&Pb[qi3 * 16 + l16][s0 + quad * 8]);
#pragma unroll
        for (int u = 0; u < 2; u++) {
            bf16x8 bv = *(const bf16x8*)(&VT[(djb + u) * 16 + l16][quad * 8]);
            oacc[u] = mfma16(pa, bv, oacc[u]);
        }
    }

#pragma unroll
    for (int u = 0; u < 2; u++) {
        const int d = (djb + u) * 16 + l16;
#pragma unroll
        for (int r = 0; r < 4; r++) {
            const int t = q0 + qi3 * 16 + quad * 4 + r;
            const float L = Lbuf[qi3 * 16 + quad * 4 + r];
            O[(size_t)(b * T_ + t) * OC + h * HD + d] = (bf16)(oacc[u][r] / L);
        }
    }
}

// ---------------------------------------------------------------------------
// Arena (~130.1 MB): W_T [0,32) | resf [32,60) | Cb/Hb [60,102/116) |
// Db [102,116) | x3b [116,130) | vecs+flag @130.
// ---------------------------------------------------------------------------
extern "C" void kernel_launch(void* const* d_in, const int* in_sizes, int n_in,
                              void* d_out, int out_size, void* d_ws, size_t ws_size,
                              hipStream_t stream) {
    const void* tgt_r  = d_in[0];
    const void* src_r  = d_in[1];
    const void* wqkv_r = d_in[2];
    const void* wpr_r  = d_in[3];
    const void* bpr_r  = d_in[4];
    const void* wkv_r  = d_in[5];
    const void* wq_r   = d_in[6];
    const void* wep_r  = d_in[7];
    const void* bep_r  = d_in[8];
    const void* fw1_r  = d_in[9];
    const void* fb1_r  = d_in[10];
    const void* fw2_r  = d_in[11];
    const void* fb2_r  = d_in[12];
    const void* l1g_r  = d_in[13];
    const void* l1b_r  = d_in[14];
    const void* l2g_r  = d_in[15];
    const void* l2b_r  = d_in[16];
    const void* l3g_r  = d_in[17];
    const void* l3b_r  = d_in[18];

    const size_t MB = 1u << 20;
    char* base = (char*)d_ws;
    bf16*  WT   = (bf16*)(base + 0 * MB);
    float* resf = (float*)(base + 32 * MB);
    bf16*  Cb   = (bf16*)(base + 60 * MB);
    bf16*  Hb   = Cb;
    bf16*  Db   = (bf16*)(base + 102 * MB);
    bf16*  x3b  = (bf16*)(base + 116 * MB);
    bf16*  vecs = (bf16*)(base + 130 * MB);
    int*   flag = (int*)(base + 130 * MB + 65536);
    bf16*  kvb  = Cb + (size_t)7168 * 1024;

    bf16* T_qkv = WT + 0;
    bf16* T_pr  = WT + 3145728;
    bf16* T_kv  = WT + 4194304;
    bf16* T_q   = WT + 6291456;
    bf16* T_ep  = WT + 7340032;
    bf16* T_f1  = WT + 8388608;
    bf16* T_f2  = WT + 12582912;

    bf16* v_bpr = vecs + 0;
    bf16* v_bep = vecs + 1024;
    bf16* v_fb1 = vecs + 2048;
    bf16* v_fb2 = vecs + 6144;
    bf16 *v_l1g = vecs + 7168,  *v_l1b = vecs + 8192;
    bf16 *v_l2g = vecs + 9216,  *v_l2b = vecs + 10240;
    bf16 *v_l3g = vecs + 11264, *v_l3b = vecs + 12288;

    const int M = 7168;
    dim3 blk(256);
    dim3 tb(32, 8);

    // 0. dtype detection, vec conversion, all weight transposes
    detect_dtype<<<1, blk, 0, stream>>>((const bf16*)tgt_r, flag);
    convert_vecs<<<52, blk, 0, stream>>>(bpr_r, bep_r, fb1_r, fb2_r, l1g_r, l1b_r,
                                         l2g_r, l2b_r, l3g_r, l3b_r, vecs, flag);
    transpose_all<<<16384, tb, 0, stream>>>(wqkv_r, wpr_r, wkv_r, wq_r, wep_r,
                                            fw1_r, fw2_r, WT, flag);

    // 1. x1 = LN1(tgt) -> Db ; x3 = LN3(tgt) -> x3b  (fused, one tgt pass)
    ln_dual<<<M, blk, 0, stream>>>(tgt_r, v_l1g, v_l1b, v_l3g, v_l3b,
                                   Db, x3b, flag);
    // 2. qkv = x1 @ wqkv  (N=3072, 1344 blocks)
    gemm_bt<128><<<24 * 56, blk, 0, stream>>>(
        Db, 1024, T_qkv, 1024, nullptr, nullptr, nullptr, Cb, nullptr, nullptr,
        flag, M, 3072, 1024, 0);
    // 3. self-attn (causal, tile-skip)
    attn_kernel<<<dim3(14, 256), blk, 0, stream>>>(Cb, 3072, Cb + 1024, 3072, Cb + 2048, 3072, Db, 1);
    // 4. resf = attn1 @ wproj + bpr + tgt  (N=1024 -> TN=64, 896 blocks)
    gemm_bt<64><<<16 * 56, blk, 0, stream>>>(
        Db, 1024, T_pr, 1024, v_bpr, tgt_r, nullptr, nullptr, resf, nullptr,
        flag, M, 1024, 1024, 0);
    // 5+6. xq = LN2(resf) -> Db ; xs = LN2(src) -> Cb  (fused launch)
    ln2_pair<<<2 * M, blk, 0, stream>>>(resf, src_r, v_l2g, v_l2b, Db, Cb, flag);
    // 7. kv = xs @ wkv  (N=2048, 896 blocks)
    gemm_bt<128><<<16 * 56, blk, 0, stream>>>(
        Cb, 1024, T_kv, 1024, nullptr, nullptr, nullptr, kvb, nullptr, nullptr,
        flag, M, 2048, 1024, 0);
    // 8. q2 = xq @ wq  (TN=64, 896 blocks)
    gemm_bt<64><<<16 * 56, blk, 0, stream>>>(
        Db, 1024, T_q, 1024, nullptr, nullptr, nullptr, Cb, nullptr, nullptr,
        flag, M, 1024, 1024, 0);
    // 9. cross-attn
    attn_kernel<<<dim3(14, 256), blk, 0, stream>>>(Cb, 1024, kvb, 2048, kvb + 1024, 2048, Db, 0);
    // 10. resf += attn2 @ wedproj + bep  (TN=64, 896 blocks, in-place)
    gemm_bt<64><<<16 * 56, blk, 0, stream>>>(
        Db, 1024, T_ep, 1024, v_bep, nullptr, resf, nullptr, resf, nullptr,
        flag, M, 1024, 1024, 0);
    // 11. h = relu(x3 @ fw1 + fb1)  (N=4096, 1792 blocks)
    gemm_bt<128><<<32 * 56, blk, 0, stream>>>(
        x3b, 1024, T_f1, 1024, v_fb1, nullptr, nullptr, Hb, nullptr, nullptr,
        flag, M, 4096, 1024, 1);
    // 12. out = h @ fw2 + fb2 + resf -> d_out  (K=4096, TN=64, 896 blocks)
    gemm_bt<64><<<16 * 56, blk, 0, stream>>>(
        Hb, 4096, T_f2, 4096, v_fb2, nullptr, resf, nullptr, nullptr, d_out,
        flag, M, 1024, 4096, 0);
}

// Round 9
// 552.311 us; speedup vs baseline: 1.1723x; 1.0460x over previous
//
#include <hip/hip_runtime.h>

typedef __bf16 bf16;
typedef __bf16 bf16x8 __attribute__((ext_vector_type(8)));
typedef float floatx4 __attribute__((ext_vector_type(4)));

__device__ __forceinline__ floatx4 mfma16(bf16x8 a, bf16x8 b, floatx4 c) {
    return __builtin_amdgcn_mfma_f32_16x16x32_bf16(a, b, c, 0, 0, 0);
}

__device__ __forceinline__ void load16_lds(const void* g, void* l) {
    __builtin_amdgcn_global_load_lds(
        (const __attribute__((address_space(1))) void*)g,
        (__attribute__((address_space(3))) void*)(unsigned int)(unsigned long long)l,
        16, 0, 0);
}

#define PIPE_BARRIER do { asm volatile("" ::: "memory"); \
    __builtin_amdgcn_s_barrier(); asm volatile("" ::: "memory"); } while (0)

// ---------------------------------------------------------------------------
// Dtype detector: fp32 buffers viewed as bf16 show wild exponents -> flag=1.
// ---------------------------------------------------------------------------
__global__ __launch_bounds__(256) void detect_dtype(const bf16* __restrict__ p,
                                                    int* __restrict__ flag) {
    __shared__ int bad;
    if (threadIdx.x == 0) bad = 0;
    __syncthreads();
    int lbad = 0;
    for (int i = threadIdx.x; i < 4096; i += 256) {
        const float v = (float)p[i];
        if (!isfinite(v) || fabsf(v) > 1e10f) lbad = 1;
    }
    if (lbad) atomicOr(&bad, 1);
    __syncthreads();
    if (threadIdx.x == 0) *flag = bad;
}

// ---------------------------------------------------------------------------
// Small vectors -> bf16 arena. bpr@0 bep@1024 fb1@2048(4096) fb2@6144
// l1g@7168 l1b@8192 l2g@9216 l2b@10240 l3g@11264 l3b@12288. 13312 total.
// ---------------------------------------------------------------------------
__global__ __launch_bounds__(256) void convert_vecs(
    const void* bpr, const void* bep, const void* fb1, const void* fb2,
    const void* g1, const void* b1, const void* g2, const void* b2,
    const void* g3, const void* b3, bf16* __restrict__ out,
    const int* __restrict__ flagp) {
    const int fl = *flagp;
    const int idx = blockIdx.x * 256 + threadIdx.x;
    const void* src;
    int off;
    if (idx < 1024)      { src = bpr; off = idx; }
    else if (idx < 2048) { src = bep; off = idx - 1024; }
    else if (idx < 6144) { src = fb1; off = idx - 2048; }
    else if (idx < 7168) { src = fb2; off = idx - 6144; }
    else {
        const void* t[6] = {g1, b1, g2, b2, g3, b3};
        src = t[(idx - 7168) >> 10];
        off = idx & 1023;
    }
    out[idx] = fl ? (bf16)((const float*)src)[off] : ((const bf16*)src)[off];
}

// ---------------------------------------------------------------------------
// Fused LN1+LN3: both normalize tgt; shared (x-mu)*rs core computed once,
// two gamma/beta applications, two outputs.
// ---------------------------------------------------------------------------
__global__ __launch_bounds__(256) void ln_dual(
    const void* __restrict__ X,
    const bf16* __restrict__ G1, const bf16* __restrict__ B1,
    const bf16* __restrict__ G3, const bf16* __restrict__ B3,
    bf16* __restrict__ Y1, bf16* __restrict__ Y3,
    const int* __restrict__ flagp) {
    const int fl = *flagp;
    const int row = blockIdx.x;
    const int tid = threadIdx.x;
    float v[4];
    if (fl) {
        const float* x = (const float*)X + (size_t)row * 1024 + tid * 4;
#pragma unroll
        for (int i = 0; i < 4; i++) v[i] = x[i];
    } else {
        const bf16* x = (const bf16*)X + (size_t)row * 1024 + tid * 4;
#pragma unroll
        for (int i = 0; i < 4; i++) v[i] = (float)x[i];
    }
    float s = v[0] + v[1] + v[2] + v[3];
    float q = v[0] * v[0] + v[1] * v[1] + v[2] * v[2] + v[3] * v[3];
#pragma unroll
    for (int off = 32; off >= 1; off >>= 1) {
        s += __shfl_xor(s, off);
        q += __shfl_xor(q, off);
    }
    __shared__ float ss[4], qq[4];
    const int wave = tid >> 6, lane = tid & 63;
    if (lane == 0) { ss[wave] = s; qq[wave] = q; }
    __syncthreads();
    s = ss[0] + ss[1] + ss[2] + ss[3];
    q = qq[0] + qq[1] + qq[2] + qq[3];
    const float mu = s * (1.0f / 1024.0f);
    const float var = q * (1.0f / 1024.0f) - mu * mu;
    const float rs = rsqrtf(var + 1e-5f);
    bf16* y1 = Y1 + (size_t)row * 1024 + tid * 4;
    bf16* y3 = Y3 + (size_t)row * 1024 + tid * 4;
#pragma unroll
    for (int i = 0; i < 4; i++) {
        const float core = (v[i] - mu) * rs;
        y1[i] = (bf16)(core * (float)G1[tid * 4 + i] + (float)B1[tid * 4 + i]);
        y3[i] = (bf16)(core * (float)G3[tid * 4 + i] + (float)B3[tid * 4 + i]);
    }
}

// ---------------------------------------------------------------------------
// Fused LN2 pair: blocks [0,7168) LN resf (always fp32) -> Yf;
// blocks [7168,14336) LN src (raw dtype per flag) -> Yr. One launch.
// ---------------------------------------------------------------------------
__global__ __launch_bounds__(256) void ln2_pair(
    const float* __restrict__ Xf, const void* __restrict__ Xr,
    const bf16* __restrict__ G, const bf16* __restrict__ Bv,
    bf16* __restrict__ Yf, bf16* __restrict__ Yr,
    const int* __restrict__ flagp) {
    const int row = blockIdx.x;
    const int tid = threadIdx.x;
    float v[4];
    bf16* y;
    if (row < 7168) {
        const float* x = Xf + (size_t)row * 1024 + tid * 4;
#pragma unroll
        for (int i = 0; i < 4; i++) v[i] = x[i];
        y = Yf + (size_t)row * 1024 + tid * 4;
    } else {
        const int r2 = row - 7168;
        if (*flagp) {
            const float* x = (const float*)Xr + (size_t)r2 * 1024 + tid * 4;
#pragma unroll
            for (int i = 0; i < 4; i++) v[i] = x[i];
        } else {
            const bf16* x = (const bf16*)Xr + (size_t)r2 * 1024 + tid * 4;
#pragma unroll
            for (int i = 0; i < 4; i++) v[i] = (float)x[i];
        }
        y = Yr + (size_t)r2 * 1024 + tid * 4;
    }
    float s = v[0] + v[1] + v[2] + v[3];
    float q = v[0] * v[0] + v[1] * v[1] + v[2] * v[2] + v[3] * v[3];
#pragma unroll
    for (int off = 32; off >= 1; off >>= 1) {
        s += __shfl_xor(s, off);
        q += __shfl_xor(q, off);
    }
    __shared__ float ss[4], qq[4];
    const int wave = tid >> 6, lane = tid & 63;
    if (lane == 0) { ss[wave] = s; qq[wave] = q; }
    __syncthreads();
    s = ss[0] + ss[1] + ss[2] + ss[3];
    q = qq[0] + qq[1] + qq[2] + qq[3];
    const float mu = s * (1.0f / 1024.0f);
    const float var = q * (1.0f / 1024.0f) - mu * mu;
    const float rs = rsqrtf(var + 1e-5f);
#pragma unroll
    for (int i = 0; i < 4; i++)
        y[i] = (bf16)((v[i] - mu) * rs * (float)G[tid * 4 + i] +
                      (float)Bv[tid * 4 + i]);
}

// ---------------------------------------------------------------------------
// One-shot transpose+convert of ALL 7 weights into the W_T arena.
// ---------------------------------------------------------------------------
__global__ __launch_bounds__(256) void transpose_all(
    const void* w0, const void* w1, const void* w2, const void* w3,
    const void* w4, const void* w5, const void* w6,
    bf16* __restrict__ out_base, const int* __restrict__ flagp) {
    const int fl = *flagp;
    const int cum[8] = {0, 3072, 4096, 6144, 7168, 8192, 12288, 16384};
    const int ntv[7] = {96, 32, 64, 32, 32, 128, 32};
    const int ldi[7] = {3072, 1024, 2048, 1024, 1024, 4096, 1024};
    const int ldo[7] = {1024, 1024, 1024, 1024, 1024, 1024, 4096};
    const size_t ooff[7] = {0, 3145728, 4194304, 6291456, 7340032, 8388608, 12582912};
    const void* ws[7] = {w0, w1, w2, w3, w4, w5, w6};

    const int g = blockIdx.x;
    int w = 0;
#pragma unroll
    for (int i = 1; i < 7; i++) if (g >= cum[i]) w = i;
    const int t = g - cum[w];
    const int xt = t % ntv[w], yt = t / ntv[w];
    const int n0 = xt * 32, k0 = yt * 32;
    const void* in = ws[w];
    bf16* out = out_base + ooff[w];
    const int ldin = ldi[w], ldout = ldo[w];

    __shared__ bf16 tile[32][33];
    const int x = threadIdx.x, y = threadIdx.y;
#pragma unroll
    for (int i = 0; i < 4; i++) {
        const size_t idx = (size_t)(k0 + y + 8 * i) * ldin + n0 + x;
        tile[y + 8 * i][x] = fl ? (bf16)((const float*)in)[idx]
                                : ((const bf16*)in)[idx];
    }
    __syncthreads();
#pragma unroll
    for (int i = 0; i < 4; i++)
        out[(size_t)(n0 + y + 8 * i) * ldout + k0 + x] = tile[x][y + 8 * i];
}

// ---------------------------------------------------------------------------
// GEMM: C[M,N] = A @ Bt^T. Tile 128 x TN, BK=64, depth-2 double-buffered
// pipeline with counted vmcnt — ROUND-4 SCHEDULE (best measured; K-loop
// frozen: drain-frequency r2, scheduler pins r1/r5, 256^2 8-phase r1/r5,
// BK=32 occupancy r7 all falsified; counted-vmcnt depth-2 was the one win).
//
// Round-9 change is LAUNCH GEOMETRY only: TN=128 for ALL GEMMs. The TN=64
// configs ran 896 blocks at 48 KiB LDS -> 3 blocks/CU -> 768 slots -> 1.17
// passes: a 128-block second pass at 14% machine fill (FFN2: 113 us =
// 64 us x 1.76 tail factor). TN=128 -> 448 blocks at 64 KiB -> 2/CU ->
// 512 slots >= 448: one full-fill pass, plus 2x MFMA per staged A-byte.
// LDS XOR-swizzle (0-conflict, verified): global source chunk c ^= row&7,
// linear gload_lds dest, matching slot XOR on ds_read.
// Epilogue: +bias, relu, +resd (raw dtype), +resf, out f32/bf16/dual.
// ---------------------------------------------------------------------------
template <int TN>
__global__ __launch_bounds__(256) void gemm_bt(
    const bf16* __restrict__ A, int lda,
    const bf16* __restrict__ Bt, int ldb,
    const bf16* __restrict__ bias,
    const void* resd,
    const float* resf,
    bf16* outb, float* outf, void* dual,
    const int* __restrict__ flagp,
    int M, int N, int K, int relu) {
    constexpr int NJ = TN / 32;
    constexpr int NB = TN / 32;
    __shared__ bf16 As[2][128 * 64];
    __shared__ bf16 Bs[2][TN * 64];
    const int fl = *flagp;
    const int tid = threadIdx.x;
    const int wave = tid >> 6, lane = tid & 63;
    const int quad = lane >> 4, l16 = lane & 15;
    const int g = blockIdx.x;
    const int yb = g % 56, xb = g / 56;
    const int m0 = yb * 128, n0 = xb * TN;
    const int wm = (wave >> 1) * 64, wn = (wave & 1) * (TN / 2);

    const int srow = tid >> 3;
    const int sc = (tid & 7) ^ (srow & 7);
    const bf16* gA = A + (size_t)(m0 + srow) * lda + sc * 8;
    const bf16* gB = Bt + (size_t)(n0 + srow) * ldb + sc * 8;

    const int NT = K >> 6;

#define STAGE_TILE(T) do { \
    const int _b = (T) & 1; \
    const int _k = (T) << 6; \
    _Pragma("unroll") \
    for (int i = 0; i < 4; i++) \
        load16_lds(gA + _k + (size_t)(32 * i) * lda, \
                   &As[_b][tid * 8 + i * 2048]); \
    _Pragma("unroll") \
    for (int i = 0; i < NB; i++) \
        load16_lds(gB + _k + (size_t)(32 * i) * ldb, \
                   &Bs[_b][tid * 8 + i * 2048]); \
} while (0)

    floatx4 acc[4][NJ] = {};

    STAGE_TILE(0);
    STAGE_TILE(1);
    if constexpr (TN == 128) asm volatile("s_waitcnt vmcnt(8)" ::: "memory");
    else                     asm volatile("s_waitcnt vmcnt(6)" ::: "memory");
    PIPE_BARRIER;

    for (int t = 0; t < NT; ++t) {
        const int cur = t & 1;
        bf16x8 af[4][2], bfr[NJ][2];
#pragma unroll
        for (int i = 0; i < 4; i++)
#pragma unroll
            for (int h = 0; h < 2; h++) {
                const int r = wm + i * 16 + l16;
                const int slot = ((h << 2) + quad) ^ (r & 7);
                af[i][h] = *(const bf16x8*)(&As[cur][r * 64 + slot * 8]);
            }
#pragma unroll
        for (int j = 0; j < NJ; j++)
#pragma unroll
            for (int h = 0; h < 2; h++) {
                const int r = wn + j * 16 + l16;
                const int slot = ((h << 2) + quad) ^ (r & 7);
                bfr[j][h] = *(const bf16x8*)(&Bs[cur][r * 64 + slot * 8]);
            }
#pragma unroll
        for (int i = 0; i < 4; i++)
#pragma unroll
            for (int j = 0; j < NJ; j++) {
                acc[i][j] = mfma16(af[i][0], bfr[j][0], acc[i][j]);
                acc[i][j] = mfma16(af[i][1], bfr[j][1], acc[i][j]);
            }
        PIPE_BARRIER;   // all waves past MFMAs => reads of buf[cur] done
        if (t + 2 < NT) {
            STAGE_TILE(t + 2);
            if constexpr (TN == 128) asm volatile("s_waitcnt vmcnt(8)" ::: "memory");
            else                     asm volatile("s_waitcnt vmcnt(6)" ::: "memory");
        } else {
            asm volatile("s_waitcnt vmcnt(0)" ::: "memory");
        }
        PIPE_BARRIER;   // buf[cur^1] (tile t+1) fully staged for all waves
    }
#undef STAGE_TILE

#pragma unroll
    for (int i = 0; i < 4; i++) {
        const int mbase = m0 + wm + i * 16 + quad * 4;
#pragma unroll
        for (int j = 0; j < NJ; j++) {
            const int n = n0 + wn + j * 16 + l16;
            const float bv = bias ? (float)bias[n] : 0.0f;
#pragma unroll
            for (int r = 0; r < 4; r++) {
                const size_t idx = (size_t)(mbase + r) * N + n;
                float v = acc[i][j][r] + bv;
                if (relu && v < 0.0f) v = 0.0f;
                if (resd) v += fl ? ((const float*)resd)[idx]
                                  : (float)((const bf16*)resd)[idx];
                if (resf) v += resf[idx];
                if (dual) {
                    if (fl) ((float*)dual)[idx] = v;
                    else ((bf16*)dual)[idx] = (bf16)v;
                } else if (outf) {
                    outf[idx] = v;
                } else {
                    outb[idx] = (bf16)v;
                }
            }
        }
    }
}

// ---------------------------------------------------------------------------
// Attention: one block per (bh, 32-query tile). 4 waves. T=448, HD=64, H=16.
// Causal tile-skip (bit-identical: masked P = 0.0 exactly).
// Round-9: PV V-load register double-buffer — the global vv load was issued
// and consumed in the same iteration (latency exposed 14x per block); now
// loaded one iteration ahead, hiding HBM/L2 latency under MFMA + syncs.
// ---------------------------------------------------------------------------
__global__ __launch_bounds__(256) void attn_kernel(
    const bf16* __restrict__ Q, int qstride,
    const bf16* __restrict__ Kp, int kstride,
    const bf16* __restrict__ Vp, int vstride,
    bf16* __restrict__ O, int causal) {
    const int T_ = 448, HD = 64, OC = 1024;
    const float scale = 0.03125f;  // C^-0.5 (full-embed scaling per reference)
    const int bh = blockIdx.y, b = bh >> 4, h = bh & 15;
    const int q0 = blockIdx.x * 32;
    const int tid = threadIdx.x, wave = tid >> 6, lane = tid & 63;
    const int quad = lane >> 4, l16 = lane & 15;

    __shared__ bf16 Pb[32][464];
    __shared__ bf16 VT[64][40];
    __shared__ float redp[32][4];
    __shared__ float Mbuf[32], Lbuf[32];

    const bf16* qb = Q + (size_t)(b * T_ + q0) * qstride + h * HD;
    const bf16* kb = Kp + (size_t)(b * T_) * kstride + h * HD;
    const bf16* vb = Vp + (size_t)(b * T_) * vstride + h * HD;

    bf16x8 qf[2][2];
#pragma unroll
    for (int qi = 0; qi < 2; qi++)
#pragma unroll
        for (int kh = 0; kh < 2; kh++)
            qf[qi][kh] = *(const bf16x8*)(qb + (size_t)(qi * 16 + l16) * qstride + kh * 32 + quad * 8);

    float S[2][7][4];
    const int tmax = q0 + 31;
#pragma unroll
    for (int kt = 0; kt < 7; kt++) {
        const int s_tile = wave * 112 + kt * 16;
        if (causal && s_tile > tmax) {
#pragma unroll
            for (int qi = 0; qi < 2; qi++)
#pragma unroll
                for (int r = 0; r < 4; r++) S[qi][kt][r] = -30000.0f;
            continue;
        }
        const int s = s_tile + l16;
        const bf16* kr = kb + (size_t)s * kstride + quad * 8;
        bf16x8 kf0 = *(const bf16x8*)kr;
        bf16x8 kf1 = *(const bf16x8*)(kr + 32);
#pragma unroll
        for (int qi = 0; qi < 2; qi++) {
            floatx4 c = {};
            c = mfma16(qf[qi][0], kf0, c);
            c = mfma16(qf[qi][1], kf1, c);
#pragma unroll
            for (int r = 0; r < 4; r++) {
                float v = c[r] * scale;
                if (causal) {
                    const int t = q0 + qi * 16 + quad * 4 + r;
                    if (s > t) v = -30000.0f;
                }
                S[qi][kt][r] = v;
            }
        }
    }

    float mx[2][4];
#pragma unroll
    for (int qi = 0; qi < 2; qi++)
#pragma unroll
        for (int r = 0; r < 4; r++) {
            float m = S[qi][0][r];
#pragma unroll
            for (int kt = 1; kt < 7; kt++) m = fmaxf(m, S[qi][kt][r]);
#pragma unroll
            for (int off = 1; off < 16; off <<= 1) m = fmaxf(m, __shfl_xor(m, off));
            mx[qi][r] = m;
        }
    if (l16 == 0) {
#pragma unroll
        for (int qi = 0; qi < 2; qi++)
#pragma unroll
            for (int r = 0; r < 4; r++) redp[qi * 16 + quad * 4 + r][wave] = mx[qi][r];
    }
    __syncthreads();
    if (tid < 32)
        Mbuf[tid] = fmaxf(fmaxf(redp[tid][0], redp[tid][1]),
                          fmaxf(redp[tid][2], redp[tid][3]));
    __syncthreads();

#pragma unroll
    for (int qi = 0; qi < 2; qi++)
#pragma unroll
        for (int r = 0; r < 4; r++) {
            const float Mv = Mbuf[qi * 16 + quad * 4 + r];
            float acc = 0.0f;
#pragma unroll
            for (int kt = 0; kt < 7; kt++) {
                const float p = __expf(fminf(S[qi][kt][r] - Mv, 0.0f));
                acc += p;
                Pb[qi * 16 + quad * 4 + r][wave * 112 + kt * 16 + l16] = (bf16)p;
            }
#pragma unroll
            for (int off = 1; off < 16; off <<= 1) acc += __shfl_xor(acc, off);
            if (l16 == 0) redp[qi * 16 + quad * 4 + r][wave] = acc;
        }
    __syncthreads();
    if (tid < 32)
        Lbuf[tid] = redp[tid][0] + redp[tid][1] + redp[tid][2] + redp[tid][3];

    floatx4 oacc[2] = {};
    const int qi3 = wave & 1, djb = (wave >> 1) * 2;
    const int ktpv = causal ? (blockIdx.x + 1) : 14;
    const bf16* vrow = vb + (size_t)(tid & 31) * vstride + (tid >> 5) * 8;
    bf16x8 vvCur = *(const bf16x8*)vrow;          // chunk 0
    bf16x8 vvNext;
    for (int kt = 0; kt < ktpv; kt++) {
        const int s0 = kt * 32;
        if (kt + 1 < ktpv)
            vvNext = *(const bf16x8*)(vrow + (size_t)(s0 + 32) * vstride);
        __syncthreads();
#pragma unroll
        for (int e = 0; e < 8; e++) VT[(tid >> 5) * 8 + e][tid & 31] = vvCur[e];
        __syncthreads();
        bf16x8 pa = *(const bf16x8*)(&Pb[qi3 * 16 + l16][s0 + quad * 8]);
#pragma unroll
        for (int u = 0; u < 2; u++) {
            bf16x8 bv = *(const bf16x8*)(&VT[(djb + u) * 16 + l16][quad * 8]);
            oacc[u] = mfma16(pa, bv, oacc[u]);
        }
        vvCur = vvNext;
    }

#pragma unroll
    for (int u = 0; u < 2; u++) {
        const int d = (djb + u) * 16 + l16;
#pragma unroll
        for (int r = 0; r < 4; r++) {
            const int t = q0 + qi3 * 16 + quad * 4 + r;
            const float L = Lbuf[qi3 * 16 + quad * 4 + r];
            O[(size_t)(b * T_ + t) * OC + h * HD + d] = (bf16)(oacc[u][r] / L);
        }
    }
}

// ---------------------------------------------------------------------------
// Arena (~130.1 MB): W_T [0,32) | resf [32,60) | Cb/Hb [60,102/116) |
// Db [102,116) | x3b [116,130) | vecs+flag @130.
// ---------------------------------------------------------------------------
extern "C" void kernel_launch(void* const* d_in, const int* in_sizes, int n_in,
                              void* d_out, int out_size, void* d_ws, size_t ws_size,
                              hipStream_t stream) {
    const void* tgt_r  = d_in[0];
    const void* src_r  = d_in[1];
    const void* wqkv_r = d_in[2];
    const void* wpr_r  = d_in[3];
    const void* bpr_r  = d_in[4];
    const void* wkv_r  = d_in[5];
    const void* wq_r   = d_in[6];
    const void* wep_r  = d_in[7];
    const void* bep_r  = d_in[8];
    const void* fw1_r  = d_in[9];
    const void* fb1_r  = d_in[10];
    const void* fw2_r  = d_in[11];
    const void* fb2_r  = d_in[12];
    const void* l1g_r  = d_in[13];
    const void* l1b_r  = d_in[14];
    const void* l2g_r  = d_in[15];
    const void* l2b_r  = d_in[16];
    const void* l3g_r  = d_in[17];
    const void* l3b_r  = d_in[18];

    const size_t MB = 1u << 20;
    char* base = (char*)d_ws;
    bf16*  WT   = (bf16*)(base + 0 * MB);
    float* resf = (float*)(base + 32 * MB);
    bf16*  Cb   = (bf16*)(base + 60 * MB);
    bf16*  Hb   = Cb;
    bf16*  Db   = (bf16*)(base + 102 * MB);
    bf16*  x3b  = (bf16*)(base + 116 * MB);
    bf16*  vecs = (bf16*)(base + 130 * MB);
    int*   flag = (int*)(base + 130 * MB + 65536);
    bf16*  kvb  = Cb + (size_t)7168 * 1024;

    bf16* T_qkv = WT + 0;
    bf16* T_pr  = WT + 3145728;
    bf16* T_kv  = WT + 4194304;
    bf16* T_q   = WT + 6291456;
    bf16* T_ep  = WT + 7340032;
    bf16* T_f1  = WT + 8388608;
    bf16* T_f2  = WT + 12582912;

    bf16* v_bpr = vecs + 0;
    bf16* v_bep = vecs + 1024;
    bf16* v_fb1 = vecs + 2048;
    bf16* v_fb2 = vecs + 6144;
    bf16 *v_l1g = vecs + 7168,  *v_l1b = vecs + 8192;
    bf16 *v_l2g = vecs + 9216,  *v_l2b = vecs + 10240;
    bf16 *v_l3g = vecs + 11264, *v_l3b = vecs + 12288;

    const int M = 7168;
    dim3 blk(256);
    dim3 tb(32, 8);

    // 0. dtype detection, vec conversion, all weight transposes
    detect_dtype<<<1, blk, 0, stream>>>((const bf16*)tgt_r, flag);
    convert_vecs<<<52, blk, 0, stream>>>(bpr_r, bep_r, fb1_r, fb2_r, l1g_r, l1b_r,
                                         l2g_r, l2b_r, l3g_r, l3b_r, vecs, flag);
    transpose_all<<<16384, tb, 0, stream>>>(wqkv_r, wpr_r, wkv_r, wq_r, wep_r,
                                            fw1_r, fw2_r, WT, flag);

    // 1. x1 = LN1(tgt) -> Db ; x3 = LN3(tgt) -> x3b  (fused, one tgt pass)
    ln_dual<<<M, blk, 0, stream>>>(tgt_r, v_l1g, v_l1b, v_l3g, v_l3b,
                                   Db, x3b, flag);
    // 2. qkv = x1 @ wqkv  (N=3072, 1344 blocks)
    gemm_bt<128><<<24 * 56, blk, 0, stream>>>(
        Db, 1024, T_qkv, 1024, nullptr, nullptr, nullptr, Cb, nullptr, nullptr,
        flag, M, 3072, 1024, 0);
    // 3. self-attn (causal, tile-skip)
    attn_kernel<<<dim3(14, 256), blk, 0, stream>>>(Cb, 3072, Cb + 1024, 3072, Cb + 2048, 3072, Db, 1);
    // 4. resf = attn1 @ wproj + bpr + tgt  (N=1024, TN=128: 448 blocks,
    //    single full-residency pass)
    gemm_bt<128><<<8 * 56, blk, 0, stream>>>(
        Db, 1024, T_pr, 1024, v_bpr, tgt_r, nullptr, nullptr, resf, nullptr,
        flag, M, 1024, 1024, 0);
    // 5+6. xq = LN2(resf) -> Db ; xs = LN2(src) -> Cb  (fused launch)
    ln2_pair<<<2 * M, blk, 0, stream>>>(resf, src_r, v_l2g, v_l2b, Db, Cb, flag);
    // 7. kv = xs @ wkv  (N=2048, 896 blocks)
    gemm_bt<128><<<16 * 56, blk, 0, stream>>>(
        Cb, 1024, T_kv, 1024, nullptr, nullptr, nullptr, kvb, nullptr, nullptr,
        flag, M, 2048, 1024, 0);
    // 8. q2 = xq @ wq  (TN=128: 448 blocks)
    gemm_bt<128><<<8 * 56, blk, 0, stream>>>(
        Db, 1024, T_q, 1024, nullptr, nullptr, nullptr, Cb, nullptr, nullptr,
        flag, M, 1024, 1024, 0);
    // 9. cross-attn
    attn_kernel<<<dim3(14, 256), blk, 0, stream>>>(Cb, 1024, kvb, 2048, kvb + 1024, 2048, Db, 0);
    // 10. resf += attn2 @ wedproj + bep  (TN=128: 448 blocks, in-place)
    gemm_bt<128><<<8 * 56, blk, 0, stream>>>(
        Db, 1024, T_ep, 1024, v_bep, nullptr, resf, nullptr, resf, nullptr,
        flag, M, 1024, 1024, 0);
    // 11. h = relu(x3 @ fw1 + fb1)  (N=4096, 1792 blocks)
    gemm_bt<128><<<32 * 56, blk, 0, stream>>>(
        x3b, 1024, T_f1, 1024, v_fb1, nullptr, nullptr, Hb, nullptr, nullptr,
        flag, M, 4096, 1024, 1);
    // 12. out = h @ fw2 + fb2 + resf -> d_out  (K=4096, TN=128: 448 blocks,
    //     single full-residency pass — was 1.17 passes w/ 14%-fill tail)
    gemm_bt<128><<<8 * 56, blk, 0, stream>>>(
        Hb, 4096, T_f2, 4096, v_fb2, nullptr, resf, nullptr, nullptr, d_out,
        flag, M, 1024, 4096, 0);
}